// Round 1
// baseline (262.717 us; speedup 1.0000x reference)
//
#include <hip/hip_runtime.h>

// Problem constants (B=16, C=512, H=W=64)
#define BATCH 16
#define C_TOT 512
#define HW    4096
#define NG    16
#define CPG   32
#define NHID  8

// ---------------------------------------------------------------------------
// Kernel 1: per-(b,c) spatial mean. One block per channel plane (8192 blocks).
// 256 threads x 4 float4 = 4096 floats per block.
// ---------------------------------------------------------------------------
__global__ __launch_bounds__(256) void pool_kernel(const float* __restrict__ x,
                                                   float* __restrict__ pooled) {
    const int bc = blockIdx.x;
    const float4* p = (const float4*)(x + (size_t)bc * HW);
    const int t = threadIdx.x;
    float s = 0.f;
#pragma unroll
    for (int i = 0; i < 4; ++i) {
        float4 v = p[t + i * 256];
        s += v.x + v.y + v.z + v.w;
    }
    // wave-64 reduction
#pragma unroll
    for (int off = 32; off > 0; off >>= 1) s += __shfl_down(s, off, 64);
    __shared__ float wsum[4];
    const int lane = t & 63, wv = t >> 6;
    if (lane == 0) wsum[wv] = s;
    __syncthreads();
    if (t == 0) {
        pooled[bc] = (wsum[0] + wsum[1] + wsum[2] + wsum[3]) * (1.0f / HW);
    }
}

// ---------------------------------------------------------------------------
// Kernel 2: all the tiny MLPs. One block per batch (16 blocks, 512 threads =
// one thread per channel). Produces fused per-output-channel scale[b,co].
//   c2 = (co%16)*32 + co/16   (second-stage channel feeding output co)
//   c1 = (c2%16)*32 + c2/16   (original channel feeding c2 via shuffle)
//   scale[b,co] = gate1[b,c1] * gate2[b,c2] * w[b, co%16]
// ---------------------------------------------------------------------------
__global__ __launch_bounds__(512) void gate_kernel(
    const float* __restrict__ pooled,
    const float* __restrict__ gw1, const float* __restrict__ gb1,
    const float* __restrict__ gw2, const float* __restrict__ gb2,
    const float* __restrict__ cw1, const float* __restrict__ cb1,
    const float* __restrict__ cw2, const float* __restrict__ cb2,
    float* __restrict__ scale) {
    const int b = blockIdx.x;
    const int c = threadIdx.x;   // 0..511

    __shared__ float p1[C_TOT], g1s[C_TOT], p2[C_TOT], g2s[C_TOT];
    __shared__ float hid[NG * NHID];
    __shared__ float glob[NG], hc[NHID], wg[NG];

    p1[c] = pooled[b * C_TOT + c];
    __syncthreads();

    // pass-1 hidden: 128 threads -> (g, o)
    if (c < NG * NHID) {
        const int g = c >> 3, o = c & 7;
        float acc = gb1[o];
#pragma unroll
        for (int k = 0; k < CPG; ++k) acc += p1[g * CPG + k] * gw1[o * CPG + k];
        hid[c] = fmaxf(acc, 0.f);
    }
    __syncthreads();

    // pass-1 gate (sigmoid), one per channel
    {
        const int g = c >> 5, cc = c & 31;
        float acc = gb2[cc];
#pragma unroll
        for (int o = 0; o < NHID; ++o) acc += hid[g * NHID + o] * gw2[cc * NHID + o];
        g1s[c] = 1.f / (1.f + expf(-acc));
    }
    __syncthreads();

    // shuffled+gated pooled for second pass: p2[c2] = p1[c1] * g1s[c1]
    {
        const int c1 = (c & 15) * CPG + (c >> 4);
        p2[c] = p1[c1] * g1s[c1];
    }
    __syncthreads();

    // pass-2 hidden
    if (c < NG * NHID) {
        const int g = c >> 3, o = c & 7;
        float acc = gb1[o];
#pragma unroll
        for (int k = 0; k < CPG; ++k) acc += p2[g * CPG + k] * gw1[o * CPG + k];
        hid[c] = fmaxf(acc, 0.f);
    }
    __syncthreads();

    // pass-2 gate
    {
        const int g = c >> 5, cc = c & 31;
        float acc = gb2[cc];
#pragma unroll
        for (int o = 0; o < NHID; ++o) acc += hid[g * NHID + o] * gw2[cc * NHID + o];
        g2s[c] = 1.f / (1.f + expf(-acc));
    }
    __syncthreads();

    // cross-gate: glob[g] = mean_cpg( p2 * g2s )
    if (c < NG) {
        float acc = 0.f;
#pragma unroll
        for (int k = 0; k < CPG; ++k) acc += p2[c * CPG + k] * g2s[c * CPG + k];
        glob[c] = acc * (1.0f / CPG);
    }
    __syncthreads();
    if (c < NHID) {
        float acc = cb1[c];
#pragma unroll
        for (int g = 0; g < NG; ++g) acc += glob[g] * cw1[c * NG + g];
        hc[c] = fmaxf(acc, 0.f);
    }
    __syncthreads();
    if (c < NG) {
        float acc = cb2[c];
#pragma unroll
        for (int j = 0; j < NHID; ++j) acc += hc[j] * cw2[c * NHID + j];
        wg[c] = 1.f / (1.f + expf(-acc));
    }
    __syncthreads();

    // fused per-output-channel scale
    {
        const int g2 = c & 15;
        const int c2 = g2 * CPG + (c >> 4);
        const int c1 = (c2 & 15) * CPG + (c2 >> 4);
        scale[b * C_TOT + c] = g1s[c1] * g2s[c2] * wg[g2];
    }
}

// ---------------------------------------------------------------------------
// Kernel 3: out[b,co,:] = x[b,c1,:] * scale[b,co]. One block per output plane.
// Reads are fully coalesced (whole contiguous source plane).
// ---------------------------------------------------------------------------
__global__ __launch_bounds__(256) void scale_kernel(const float* __restrict__ x,
                                                    const float* __restrict__ scale,
                                                    float* __restrict__ out) {
    const int bc = blockIdx.x;
    const int b = bc >> 9;
    const int co = bc & 511;
    const int c2 = (co & 15) * CPG + (co >> 4);
    const int c1 = (c2 & 15) * CPG + (c2 >> 4);
    const float s = scale[bc];
    const float4* src = (const float4*)(x + ((size_t)b * C_TOT + c1) * HW);
    float4* dst = (float4*)(out + (size_t)bc * HW);
    const int t = threadIdx.x;
#pragma unroll
    for (int i = 0; i < 4; ++i) {
        float4 v = src[t + i * 256];
        v.x *= s; v.y *= s; v.z *= s; v.w *= s;
        dst[t + i * 256] = v;
    }
}

extern "C" void kernel_launch(void* const* d_in, const int* in_sizes, int n_in,
                              void* d_out, int out_size, void* d_ws, size_t ws_size,
                              hipStream_t stream) {
    const float* x   = (const float*)d_in[0];
    const float* gw1 = (const float*)d_in[1];
    const float* gb1 = (const float*)d_in[2];
    const float* gw2 = (const float*)d_in[3];
    const float* gb2 = (const float*)d_in[4];
    const float* cw1 = (const float*)d_in[5];
    const float* cb1 = (const float*)d_in[6];
    const float* cw2 = (const float*)d_in[7];
    const float* cb2 = (const float*)d_in[8];
    float* out = (float*)d_out;

    float* pooled = (float*)d_ws;            // BATCH*C_TOT floats
    float* scale  = pooled + BATCH * C_TOT;  // BATCH*C_TOT floats

    pool_kernel<<<BATCH * C_TOT, 256, 0, stream>>>(x, pooled);
    gate_kernel<<<BATCH, 512, 0, stream>>>(pooled, gw1, gb1, gw2, gb2,
                                           cw1, cb1, cw2, cb2, scale);
    scale_kernel<<<BATCH * C_TOT, 256, 0, stream>>>(x, scale, out);
}

// Round 3
// 262.387 us; speedup vs baseline: 1.0013x; 1.0013x over previous
//
#include <hip/hip_runtime.h>

// Problem constants (B=16, C=512, H=W=64)
#define BATCH 16
#define C_TOT 512
#define HW    4096
#define NG    16
#define CPG   32
#define NHID  8

typedef float f32x4 __attribute__((ext_vector_type(4)));

// ---------------------------------------------------------------------------
// Kernel 1: per-(b,c) spatial mean. One block per channel plane (8192 blocks).
// 256 threads x 4 float4 = 4096 floats per block. Regular (caching) loads so
// x becomes L3-resident for kernel 3.
// ---------------------------------------------------------------------------
__global__ __launch_bounds__(256) void pool_kernel(const float* __restrict__ x,
                                                   float* __restrict__ pooled) {
    const int bc = blockIdx.x;
    const f32x4* p = (const f32x4*)(x + (size_t)bc * HW);
    const int t = threadIdx.x;
    float s = 0.f;
#pragma unroll
    for (int i = 0; i < 4; ++i) {
        f32x4 v = p[t + i * 256];
        s += v.x + v.y + v.z + v.w;
    }
    // wave-64 reduction
#pragma unroll
    for (int off = 32; off > 0; off >>= 1) s += __shfl_down(s, off, 64);
    __shared__ float wsum[4];
    const int lane = t & 63, wv = t >> 6;
    if (lane == 0) wsum[wv] = s;
    __syncthreads();
    if (t == 0) {
        pooled[bc] = (wsum[0] + wsum[1] + wsum[2] + wsum[3]) * (1.0f / HW);
    }
}

// ---------------------------------------------------------------------------
// Kernel 2: all the tiny MLPs. One block per batch (16 blocks, 512 threads =
// one thread per channel). Produces fused per-output-channel scale[b,co].
//   c2 = (co%16)*32 + co/16   (second-stage channel feeding output co)
//   c1 = (c2%16)*32 + c2/16   (original channel feeding c2 via shuffle)
//   scale[b,co] = gate1[b,c1] * gate2[b,c2] * w[b, co%16]
// ---------------------------------------------------------------------------
__global__ __launch_bounds__(512) void gate_kernel(
    const float* __restrict__ pooled,
    const float* __restrict__ gw1, const float* __restrict__ gb1,
    const float* __restrict__ gw2, const float* __restrict__ gb2,
    const float* __restrict__ cw1, const float* __restrict__ cb1,
    const float* __restrict__ cw2, const float* __restrict__ cb2,
    float* __restrict__ scale) {
    const int b = blockIdx.x;
    const int c = threadIdx.x;   // 0..511

    __shared__ float p1[C_TOT], g1s[C_TOT], p2[C_TOT], g2s[C_TOT];
    __shared__ float hid[NG * NHID];
    __shared__ float glob[NG], hc[NHID], wg[NG];

    p1[c] = pooled[b * C_TOT + c];
    __syncthreads();

    // pass-1 hidden: 128 threads -> (g, o)
    if (c < NG * NHID) {
        const int g = c >> 3, o = c & 7;
        float acc = gb1[o];
#pragma unroll
        for (int k = 0; k < CPG; ++k) acc += p1[g * CPG + k] * gw1[o * CPG + k];
        hid[c] = fmaxf(acc, 0.f);
    }
    __syncthreads();

    // pass-1 gate (sigmoid), one per channel
    {
        const int g = c >> 5, cc = c & 31;
        float acc = gb2[cc];
#pragma unroll
        for (int o = 0; o < NHID; ++o) acc += hid[g * NHID + o] * gw2[cc * NHID + o];
        g1s[c] = 1.f / (1.f + expf(-acc));
    }
    __syncthreads();

    // shuffled+gated pooled for second pass: p2[c2] = p1[c1] * g1s[c1]
    {
        const int c1 = (c & 15) * CPG + (c >> 4);
        p2[c] = p1[c1] * g1s[c1];
    }
    __syncthreads();

    // pass-2 hidden
    if (c < NG * NHID) {
        const int g = c >> 3, o = c & 7;
        float acc = gb1[o];
#pragma unroll
        for (int k = 0; k < CPG; ++k) acc += p2[g * CPG + k] * gw1[o * CPG + k];
        hid[c] = fmaxf(acc, 0.f);
    }
    __syncthreads();

    // pass-2 gate
    {
        const int g = c >> 5, cc = c & 31;
        float acc = gb2[cc];
#pragma unroll
        for (int o = 0; o < NHID; ++o) acc += hid[g * NHID + o] * gw2[cc * NHID + o];
        g2s[c] = 1.f / (1.f + expf(-acc));
    }
    __syncthreads();

    // cross-gate: glob[g] = mean_cpg( p2 * g2s )
    if (c < NG) {
        float acc = 0.f;
#pragma unroll
        for (int k = 0; k < CPG; ++k) acc += p2[c * CPG + k] * g2s[c * CPG + k];
        glob[c] = acc * (1.0f / CPG);
    }
    __syncthreads();
    if (c < NHID) {
        float acc = cb1[c];
#pragma unroll
        for (int g = 0; g < NG; ++g) acc += glob[g] * cw1[c * NG + g];
        hc[c] = fmaxf(acc, 0.f);
    }
    __syncthreads();
    if (c < NG) {
        float acc = cb2[c];
#pragma unroll
        for (int j = 0; j < NHID; ++j) acc += hc[j] * cw2[c * NHID + j];
        wg[c] = 1.f / (1.f + expf(-acc));
    }
    __syncthreads();

    // fused per-output-channel scale
    {
        const int g2 = c & 15;
        const int c2 = g2 * CPG + (c >> 4);
        const int c1 = (c2 & 15) * CPG + (c2 >> 4);
        scale[b * C_TOT + c] = g1s[c1] * g2s[c2] * wg[g2];
    }
}

// ---------------------------------------------------------------------------
// Kernel 3: out[b,co,:] = x[b,c1,:] * scale[b,co]. One block per output plane.
// x reads hit the L3 (populated by kernel 1); out writes are NONTEMPORAL so
// they bypass/minimally-disturb the caches and keep x resident.
// ---------------------------------------------------------------------------
__global__ __launch_bounds__(256) void scale_kernel(const float* __restrict__ x,
                                                    const float* __restrict__ scale,
                                                    float* __restrict__ out) {
    const int bc = blockIdx.x;
    const int b = bc >> 9;
    const int co = bc & 511;
    const int c2 = (co & 15) * CPG + (co >> 4);
    const int c1 = (c2 & 15) * CPG + (c2 >> 4);
    const float s = scale[bc];
    const f32x4* src = (const f32x4*)(x + ((size_t)b * C_TOT + c1) * HW);
    f32x4* dst = (f32x4*)(out + (size_t)bc * HW);
    const int t = threadIdx.x;
#pragma unroll
    for (int i = 0; i < 4; ++i) {
        f32x4 v = src[t + i * 256];
        v *= s;
        __builtin_nontemporal_store(v, &dst[t + i * 256]);
    }
}

extern "C" void kernel_launch(void* const* d_in, const int* in_sizes, int n_in,
                              void* d_out, int out_size, void* d_ws, size_t ws_size,
                              hipStream_t stream) {
    const float* x   = (const float*)d_in[0];
    const float* gw1 = (const float*)d_in[1];
    const float* gb1 = (const float*)d_in[2];
    const float* gw2 = (const float*)d_in[3];
    const float* gb2 = (const float*)d_in[4];
    const float* cw1 = (const float*)d_in[5];
    const float* cb1 = (const float*)d_in[6];
    const float* cw2 = (const float*)d_in[7];
    const float* cb2 = (const float*)d_in[8];
    float* out = (float*)d_out;

    float* pooled = (float*)d_ws;            // BATCH*C_TOT floats
    float* scale  = pooled + BATCH * C_TOT;  // BATCH*C_TOT floats

    pool_kernel<<<BATCH * C_TOT, 256, 0, stream>>>(x, pooled);
    gate_kernel<<<BATCH, 512, 0, stream>>>(pooled, gw1, gb1, gw2, gb2,
                                           cw1, cb1, cw2, cb2, scale);
    scale_kernel<<<BATCH * C_TOT, 256, 0, stream>>>(x, scale, out);
}